// Round 6
// baseline (425.185 us; speedup 1.0000x reference)
//
#include <hip/hip_runtime.h>
#include <cstdint>
#include <cstddef>

// ---------------------------------------------------------------------------
// MemoryN2N on MI355X.
// Pipeline:
//  K1  transpose+l2norm x -> xn (bf16, n x 256) + per-node norms (f32)
//  K2  l2norm feat_w[:, :256] -> mn (bf16, k x 256)
//  G1  argmax-only: S = xn @ mn^T per tile -> packed_part planes (NO Q store,
//      NO lrow -- Q round-trip (137MB w + 128MB r) was the round-5 floor)
//  K4  ind = merge 16 planes -> ind, cnt
//  S1/S2/S3  counting-sort + contiguous segment sums
//  K6  new_w EMA + l2norm -> nwt (bf16, transposed, 384 rows padded)
//  K7a c0, zc, hc, oc constant path (f32 exact)   K7b w1^T,w2^T -> bf16
//  A   attn_kernel (FUSED, replaces gemm2): per 64-row block, loop 16 nt:
//      recompute S (same MFMA accumulation order as G1 -> same values),
//      P = exp(S)-1 -> LDS (A-operand layout), O += P @ nwt-tile,
//      row-sums of P accumulated in regs. Epilogue: d = (colsum+O)/l - c0.
//  G3  z = zc + d@w1t; e = gelu(z)-hc -> ebuf
//  G4  o = oc + e@w2t -> fused transpose-store to out (b,256,64,64)
// GEMM core (G1/G3/G4): global_load_lds width=16, two K=32 slices per barrier,
// 128x128 tile, 16x16x32 bf16 MFMA. attn_kernel uses the same m97-style
// pitch-32-chunk LDS layout for all staged operands and for P.
// ---------------------------------------------------------------------------

typedef short v8s __attribute__((ext_vector_type(8)));
typedef float v4f __attribute__((ext_vector_type(4)));

__device__ __forceinline__ unsigned short f2b(float f) {
  unsigned u = __float_as_uint(f);
  u = (u + 0x7FFFu + ((u >> 16) & 1u)) >> 16;  // RNE to bf16
  return (unsigned short)u;
}
__device__ __forceinline__ float b2f(short s) {
  return __uint_as_float((unsigned)(unsigned short)s << 16);
}
__device__ __forceinline__ float gelu_t(float x) {
  float x3 = x * x * x;
  return 0.5f * x * (1.0f + tanhf(0.7978845608028654f * (x + 0.044715f * x3)));
}
__device__ __forceinline__ float gelu_fast(float x) {
  float u = 0.7978845608028654f * (x + 0.044715f * x * x * x);
  float tt = __expf(2.0f * u);
  return x * tt * __builtin_amdgcn_rcpf(tt + 1.0f);
}
__device__ __forceinline__ unsigned int mono(float f) {
  unsigned u = __float_as_uint(f);
  return (u & 0x80000000u) ? ~u : (u | 0x80000000u);  // order-preserving map
}
__device__ __forceinline__ void async16(const short* g, short* l) {
  __builtin_amdgcn_global_load_lds(
      (const __attribute__((address_space(1))) unsigned int*)g,
      (__attribute__((address_space(3))) unsigned int*)l, 16, 0, 0);
}

// ------------------------------ K1: x -> xn --------------------------------
__global__ void transpose_norm_kernel(const float* __restrict__ x, short* __restrict__ xn,
                                      float* __restrict__ norms) {
  __shared__ float tile[32 * 257];
  __shared__ float part[8][32];
  __shared__ float invn[32];
  int t = threadIdx.x, bx = blockIdx.x;           // grid 1024 = 8 b * 128 stiles
  int b = bx >> 7, st = bx & 127;
  int s0 = st * 32;
  int sl = t & 31, cp = t >> 5;
  const float* xb = x + (size_t)b * 256 * 4096 + s0 + sl;
  float ss = 0.f;
#pragma unroll 4
  for (int i = 0; i < 32; ++i) {
    int c = cp * 32 + i;
    float v = xb[(size_t)c * 4096];
    tile[sl * 257 + c] = v;
    ss += v * v;
  }
  part[cp][sl] = ss;
  __syncthreads();
  if (t < 32) {
    float tot = 0.f;
#pragma unroll
    for (int p = 0; p < 8; ++p) tot += part[p][t];
    float nrm = fmaxf(sqrtf(tot), 1e-12f);
    invn[t] = 1.0f / nrm;
    norms[(size_t)b * 4096 + s0 + t] = nrm;
  }
  __syncthreads();
  size_t obase = ((size_t)b * 4096 + s0) * 256 + t;
  for (int s = 0; s < 32; ++s)
    xn[obase + (size_t)s * 256] = (short)f2b(tile[s * 257 + t] * invn[s]);
}

// --------------------------- K2: feat_w -> mn ------------------------------
__global__ void cbnorm_kernel(const float* __restrict__ fw, short* __restrict__ mn) {
  int t = threadIdx.x;
  int wv = t >> 6, l = t & 63;
  int r = blockIdx.x * 4 + wv;
  const float* row = fw + (size_t)r * 260;
  float v[4]; float ss = 0.f;
#pragma unroll
  for (int p = 0; p < 4; ++p) { v[p] = row[l + p * 64]; ss += v[p] * v[p]; }
#pragma unroll
  for (int m = 1; m < 64; m <<= 1) ss += __shfl_xor(ss, m, 64);
  float inv = 1.0f / fmaxf(sqrtf(ss), 1e-12f);
#pragma unroll
  for (int p = 0; p < 4; ++p) mn[(size_t)r * 256 + l + p * 64] = (short)f2b(v[p] * inv);
}

// ------------------------- shared bt-GEMM core -----------------------------
template <int KTOT, int LDA, int LDB>
__device__ __forceinline__ void gemm_core2(const short* __restrict__ A, const short* __restrict__ B,
                                           int mt, int nt, int t, v4f acc[4][4],
                                           short* smem) {
  short* As = smem;
  short* Bs = smem + 4096;
  const int l = t & 63, w = t >> 6;
  const int wm = w >> 1, wn = w & 1;
  const int lane16 = l & 15, q4 = l >> 4;
#pragma unroll
  for (int i = 0; i < 4; ++i)
#pragma unroll
    for (int j = 0; j < 4; ++j)
#pragma unroll
      for (int r = 0; r < 4; ++r) acc[i][j][r] = 0.0f;
  const int srow = (w << 5) + (l >> 2);
  const int scol = (l & 3) << 3;
  const short* ga = A + (size_t)(mt * 128 + srow) * LDA + scol;
  const short* gb = B + (size_t)(nt * 128 + srow) * LDB + scol;
  short* la = As + (w << 5) * 32;
  short* lb = Bs + (w << 5) * 32;
  int kk = 0;
  for (; kk + 64 <= KTOT; kk += 64) {
    async16(ga + kk, la);
    async16(ga + (size_t)16 * LDA + kk, la + 512);
    async16(gb + kk, lb);
    async16(gb + (size_t)16 * LDB + kk, lb + 512);
    async16(ga + kk + 32, la + 8192);
    async16(ga + (size_t)16 * LDA + kk + 32, la + 8704);
    async16(gb + kk + 32, lb + 8192);
    async16(gb + (size_t)16 * LDB + kk + 32, lb + 8704);
    __syncthreads();
    v8s af[4], bf[4];
#pragma unroll
    for (int i = 0; i < 4; ++i) af[i] = *(const v8s*)&As[(wm * 64 + i * 16 + lane16) * 32 + q4 * 8];
#pragma unroll
    for (int j = 0; j < 4; ++j) bf[j] = *(const v8s*)&Bs[(wn * 64 + j * 16 + lane16) * 32 + q4 * 8];
#pragma unroll
    for (int i = 0; i < 4; ++i)
#pragma unroll
      for (int j = 0; j < 4; ++j)
        acc[i][j] = __builtin_amdgcn_mfma_f32_16x16x32_bf16(af[i], bf[j], acc[i][j], 0, 0, 0);
#pragma unroll
    for (int i = 0; i < 4; ++i) af[i] = *(const v8s*)&As[8192 + (wm * 64 + i * 16 + lane16) * 32 + q4 * 8];
#pragma unroll
    for (int j = 0; j < 4; ++j) bf[j] = *(const v8s*)&Bs[8192 + (wn * 64 + j * 16 + lane16) * 32 + q4 * 8];
#pragma unroll
    for (int i = 0; i < 4; ++i)
#pragma unroll
      for (int j = 0; j < 4; ++j)
        acc[i][j] = __builtin_amdgcn_mfma_f32_16x16x32_bf16(af[i], bf[j], acc[i][j], 0, 0, 0);
    __syncthreads();
  }
  if (kk < KTOT) {
    async16(ga + kk, la);
    async16(ga + (size_t)16 * LDA + kk, la + 512);
    async16(gb + kk, lb);
    async16(gb + (size_t)16 * LDB + kk, lb + 512);
    __syncthreads();
    v8s af[4], bf[4];
#pragma unroll
    for (int i = 0; i < 4; ++i) af[i] = *(const v8s*)&As[(wm * 64 + i * 16 + lane16) * 32 + q4 * 8];
#pragma unroll
    for (int j = 0; j < 4; ++j) bf[j] = *(const v8s*)&Bs[(wn * 64 + j * 16 + lane16) * 32 + q4 * 8];
#pragma unroll
    for (int i = 0; i < 4; ++i)
#pragma unroll
      for (int j = 0; j < 4; ++j)
        acc[i][j] = __builtin_amdgcn_mfma_f32_16x16x32_bf16(af[i], bf[j], acc[i][j], 0, 0, 0);
    __syncthreads();
  }
}

#define CP 136

// ---------------- G1: argmax-only score GEMM -------------------------------
__global__ __launch_bounds__(256, 4) void gemm1_kernel(const short* __restrict__ A, const short* __restrict__ B,
                                                       unsigned long long* __restrict__ packed_part) {
  __shared__ __align__(16) short smem[16384];
  __shared__ unsigned long long partk[128][2];
  int t = threadIdx.x, bx = blockIdx.x;           // grid 4096, nt-major
  int nt = bx >> 8, mt = bx & 255;
  v4f acc[4][4];
  gemm_core2<256, 256, 256>(A, B, mt, nt, t, acc, smem);
  int l = t & 63, w = t >> 6, wm = w >> 1, wn = w & 1, lane16 = l & 15, q4 = l >> 4;
  int rowbase = mt * 128, colbase = nt * 128;
#pragma unroll
  for (int i = 0; i < 4; ++i) {
#pragma unroll
    for (int r = 0; r < 4; ++r) {
      int lr = wm * 64 + i * 16 + q4 * 4 + r;
      unsigned long long best = 0ull;
#pragma unroll
      for (int j = 0; j < 4; ++j) {
        float s = acc[i][j][r];
        int col_g = colbase + wn * 64 + j * 16 + lane16;
        unsigned long long key = ((unsigned long long)mono(s) << 32) |
                                 (unsigned long long)(unsigned int)(~(unsigned)col_g);
        if (key > best) best = key;               // ties -> smaller col wins
      }
#pragma unroll
      for (int m = 1; m < 16; m <<= 1) {
        unsigned long long ob = __shfl_xor(best, m, 64);
        if (ob > best) best = ob;
      }
      if (lane16 == 0) partk[lr][wn] = best;
    }
  }
  __syncthreads();
  if (t < 128) {
    unsigned long long b0 = partk[t][0], b1 = partk[t][1];
    packed_part[((size_t)nt << 15) + rowbase + t] = (b1 > b0) ? b1 : b0;
  }
}

// ----------------- K4: merge planes -> ind, counts -------------------------
__global__ void ind_kernel(const unsigned long long* __restrict__ packed_part,
                           int* __restrict__ ind, float* __restrict__ cnt) {
  int i = blockIdx.x * 256 + threadIdx.x;
  unsigned long long best = 0ull;
#pragma unroll
  for (int nt = 0; nt < 16; ++nt) {
    unsigned long long v = packed_part[((size_t)nt << 15) + i];
    if (v > best) best = v;
  }
  int id = (int)(~(unsigned int)(best & 0xFFFFFFFFull));
  ind[i] = id;
  atomicAdd(&cnt[id], 1.0f);
}

// ----------------- S1: exclusive scan of counts (1 block) ------------------
__global__ void scan_kernel(const float* __restrict__ cnt, int* __restrict__ offs,
                            int* __restrict__ cursor) {
  __shared__ int part[256];
  int t = threadIdx.x;
  int local[8]; int s = 0;
#pragma unroll
  for (int i = 0; i < 8; ++i) { local[i] = s; s += (int)cnt[t * 8 + i]; }
  part[t] = s;
  __syncthreads();
  for (int off = 1; off < 256; off <<= 1) {
    int v = (t >= off) ? part[t - off] : 0;
    __syncthreads();
    part[t] += v;
    __syncthreads();
  }
  int base = (t > 0) ? part[t - 1] : 0;
#pragma unroll
  for (int i = 0; i < 8; ++i) {
    int o = base + local[i];
    offs[t * 8 + i] = o;
    cursor[t * 8 + i] = o;
  }
  if (t == 255) offs[2048] = part[255];
}

// ------------------- S2: counting-sort node ids by ind ---------------------
__global__ void fill_kernel(const int* __restrict__ ind, int* __restrict__ cursor,
                            int* __restrict__ sorted) {
  int i = blockIdx.x * 256 + threadIdx.x;
  int id = ind[i];
  int pos = atomicAdd(&cursor[id], 1);
  sorted[pos] = i;
}

// ---------------- S3: contiguous segment sums (no atomics) -----------------
__global__ void segsum_kernel(const short* __restrict__ xn, const float* __restrict__ norms,
                              const float* __restrict__ y, const int* __restrict__ offs,
                              const int* __restrict__ sorted, float* __restrict__ sums) {
  int r = blockIdx.x, t = threadIdx.x;
  int beg = offs[r], end = offs[r + 1];
  float a0 = 0.f, a1 = 0.f;
  for (int j = beg; j < end; ++j) {
    int node = sorted[j];
    float nm = norms[node];
    a0 += b2f(xn[(size_t)node * 256 + t]) * nm;
    if (t < 4) {
      int b = node >> 12, s = node & 4095;
      a1 += y[(size_t)b * 16384 + t * 4096 + s];
    }
  }
  sums[(size_t)r * 260 + t] = a0;
  if (t < 4) sums[(size_t)r * 260 + 256 + t] = a1;
}

// --------------------- K6: EMA + l2norm -> nwt, colsum ---------------------
__global__ void neww_kernel(const float* __restrict__ fw, const float* __restrict__ sums,
                            const float* __restrict__ cnt, short* __restrict__ nwt,
                            float* __restrict__ colsum) {
  int r = blockIdx.x;
  int l = threadIdx.x;
  float cv = cnt[r] + 1e-6f;
  float vals[5]; float ss = 0.f;
#pragma unroll
  for (int p = 0; p < 5; ++p) {
    int c = l + p * 64;
    float v = 0.f;
    if (c < 260) {
      float m = sums[(size_t)r * 260 + c] / cv;
      v = fw[(size_t)r * 260 + c] * 0.999f + m * 0.001f;
    }
    vals[p] = v; ss += v * v;
  }
#pragma unroll
  for (int m = 1; m < 64; m <<= 1) ss += __shfl_xor(ss, m, 64);
  float inv = 1.0f / fmaxf(sqrtf(ss), 1e-12f);
#pragma unroll
  for (int p = 0; p < 5; ++p) {
    int c = l + p * 64;
    if (c < 260) {
      float v = vals[p] * inv;
      nwt[(size_t)c * 2048 + r] = (short)f2b(v);
      atomicAdd(&colsum[c], v);
    }
  }
}

// ------------- K7a: constant path c0, zc, hc, oc (f32 exact) ---------------
__global__ void const_kernel(const float* __restrict__ colsum, const float* __restrict__ w1,
                             const float* __restrict__ b1, const float* __restrict__ w2,
                             const float* __restrict__ b2, float* __restrict__ c0,
                             float* __restrict__ zc, float* __restrict__ hc,
                             float* __restrict__ oc) {
  __shared__ float c0s[260], hcs[256];
  int t = threadIdx.x;
  for (int c = t; c < 260; c += 256) {
    float v = colsum[c] * (1.0f / 2048.0f);
    c0s[c] = v; c0[c] = v;
  }
  __syncthreads();
  float z = b1[t];
  for (int i = 0; i < 260; ++i) z = fmaf(c0s[i], w1[(size_t)i * 256 + t], z);
  float h = gelu_t(z);
  zc[t] = z; hc[t] = h; hcs[t] = h;
  __syncthreads();
  float o = b2[t];
  for (int i = 0; i < 256; ++i) o = fmaf(hcs[i], w2[(size_t)i * 256 + t], o);
  oc[t] = o;
}

// -------------------- K7b: weight transposes to bf16 -----------------------
__global__ void wtrans_kernel(const float* __restrict__ w1, const float* __restrict__ w2,
                              short* __restrict__ w1t, short* __restrict__ w2t) {
  int j = blockIdx.x;
  int t = threadIdx.x;
  if (j < 256) {
    for (int i = t; i < 288; i += 64)
      w1t[(size_t)j * 288 + i] = (short)f2b(i < 260 ? w1[(size_t)i * 256 + j] : 0.0f);
  } else {
    int jj = j - 256;
    for (int i = t; i < 256; i += 64)
      w2t[(size_t)jj * 256 + i] = (short)f2b(w2[(size_t)i * 256 + jj]);
  }
}

// --------- A: fused attention (S recompute + P@nw), replaces gemm2 --------
// Block = 64 query rows. LDS map (shorts): region1 [0,24576) holds xn-half
// [0,8192) + mn-half [8192,24576) during S, then nwt halves [0,20480) during
// PV, then d-tile 64x296 [0,18944) in the epilogue. P [24576,32768).
__global__ __launch_bounds__(256, 2) void attn_kernel(const short* __restrict__ xn,
                                                      const short* __restrict__ mn,
                                                      const short* __restrict__ nwt,
                                                      const float* __restrict__ colsum,
                                                      const float* __restrict__ c0,
                                                      short* __restrict__ D) {
  __shared__ __align__(16) short smem[32768];
  __shared__ float lsum[64];
  int t = threadIdx.x, mt = blockIdx.x;           // grid 512
  int l = t & 63, w = t >> 6;
  int lane16 = l & 15, q4 = l >> 4;
  if (t < 64) lsum[t] = 0.f;
  v4f acc_o[4][5];
#pragma unroll
  for (int rt = 0; rt < 4; ++rt)
#pragma unroll
    for (int j = 0; j < 5; ++j)
#pragma unroll
      for (int r = 0; r < 4; ++r) acc_o[rt][j][r] = 0.0f;
  float qs_acc[4][4];
#pragma unroll
  for (int rt = 0; rt < 4; ++rt)
#pragma unroll
    for (int r = 0; r < 4; ++r) qs_acc[rt][r] = 0.0f;
  const int lrow4 = l >> 2, lc8 = (l & 3) << 3;

  for (int nt = 0; nt < 16; ++nt) {
    __syncthreads();                              // region1 + P reuse guard
    v4f acc_s[4][2];
#pragma unroll
    for (int rt = 0; rt < 4; ++rt)
#pragma unroll
      for (int ct = 0; ct < 2; ++ct)
#pragma unroll
        for (int r = 0; r < 4; ++r) acc_s[rt][ct][r] = 0.0f;
    for (int kh = 0; kh < 2; ++kh) {
      // stage xn-half (wave w = kslice w): 4 slabs of 16 rows
#pragma unroll
      for (int s = 0; s < 4; ++s)
        async16(xn + (size_t)(mt * 64 + s * 16 + lrow4) * 256 + kh * 128 + w * 32 + lc8,
                &smem[w * 2048 + s * 512]);
      // stage mn-half: 8 slabs of 16 rows
#pragma unroll
      for (int s = 0; s < 8; ++s)
        async16(mn + (size_t)(nt * 128 + s * 16 + lrow4) * 256 + kh * 128 + w * 32 + lc8,
                &smem[8192 + w * 4096 + s * 512]);
      __syncthreads();
#pragma unroll
      for (int ks = 0; ks < 4; ++ks) {
        v8s a[4], b[2];
#pragma unroll
        for (int rt = 0; rt < 4; ++rt)
          a[rt] = *(const v8s*)&smem[ks * 2048 + rt * 512 + lane16 * 32 + q4 * 8];
#pragma unroll
        for (int ct = 0; ct < 2; ++ct)
          b[ct] = *(const v8s*)&smem[8192 + ks * 4096 + (2 * w + ct) * 512 + lane16 * 32 + q4 * 8];
#pragma unroll
        for (int rt = 0; rt < 4; ++rt)
#pragma unroll
          for (int ct = 0; ct < 2; ++ct)
            acc_s[rt][ct] = __builtin_amdgcn_mfma_f32_16x16x32_bf16(a[rt], b[ct], acc_s[rt][ct], 0, 0, 0);
      }
      __syncthreads();
    }
    // S epilogue: P = exp(S)-1 -> P-LDS (A-layout), accumulate row sums
#pragma unroll
    for (int rt = 0; rt < 4; ++rt)
#pragma unroll
      for (int ct = 0; ct < 2; ++ct)
#pragma unroll
        for (int r = 0; r < 4; ++r) {
          float qv = __expf(acc_s[rt][ct][r]) - 1.0f;
          qs_acc[rt][r] += qv;
          smem[24576 + w * 2048 + rt * 512 + (q4 * 4 + r) * 32 + ct * 16 + lane16] = (short)f2b(qv);
        }
    __syncthreads();                              // P visible; region1 free
    for (int h = 0; h < 2; ++h) {
      // stage nwt K=64 half: 2 kslices x 20 slabs (320 rows incl. zero pad)
      int idbase = w * 10;
#pragma unroll
      for (int u = 0; u < 10; ++u) {
        int id = idbase + u;
        int ks2 = (id >= 20) ? 1 : 0;
        int slab = id - ks2 * 20;
        async16(nwt + (size_t)(slab * 16 + lrow4) * 2048 + nt * 128 + h * 64 + ks2 * 32 + lc8,
                &smem[ks2 * 10240 + slab * 512]);
      }
      __syncthreads();
#pragma unroll
      for (int ks2 = 0; ks2 < 2; ++ks2) {
        int kg = h * 2 + ks2;
        v8s a[4], b[5];
#pragma unroll
        for (int rt = 0; rt < 4; ++rt)
          a[rt] = *(const v8s*)&smem[24576 + kg * 2048 + rt * 512 + lane16 * 32 + q4 * 8];
#pragma unroll
        for (int j = 0; j < 5; ++j)
          b[j] = *(const v8s*)&smem[ks2 * 10240 + (w * 5 + j) * 512 + lane16 * 32 + q4 * 8];
#pragma unroll
        for (int rt = 0; rt < 4; ++rt)
#pragma unroll
          for (int j = 0; j < 5; ++j)
            acc_o[rt][j] = __builtin_amdgcn_mfma_f32_16x16x32_bf16(a[rt], b[j], acc_o[rt][j], 0, 0, 0);
      }
      __syncthreads();
    }
  }
  // merge row sums
#pragma unroll
  for (int rt = 0; rt < 4; ++rt)
#pragma unroll
    for (int r = 0; r < 4; ++r) {
      float v = qs_acc[rt][r];
#pragma unroll
      for (int m = 1; m < 16; m <<= 1) v += __shfl_xor(v, m, 64);
      if (lane16 == 0) atomicAdd(&lsum[rt * 16 + q4 * 4 + r], v);
    }
  __syncthreads();
  // d epilogue into d-tile (64 x 296 pitch), then wide stores
#pragma unroll
  for (int rt = 0; rt < 4; ++rt)
#pragma unroll
    for (int r = 0; r < 4; ++r) {
      int m = rt * 16 + q4 * 4 + r;
      float linv = 1.0f / (2048.0f + lsum[m]);
#pragma unroll
      for (int j = 0; j < 5; ++j) {
        int c = w * 80 + j * 16 + lane16;
        if (c < 288) {
          float v = 0.0f;
          if (c < 260) v = (colsum[c] + acc_o[rt][j][r]) * linv - c0[c];
          smem[m * 296 + c] = (short)f2b(v);
        }
      }
    }
  __syncthreads();
#pragma unroll
  for (int k2 = 0; k2 < 9; ++k2) {
    int idx = k2 * 256 + t;                       // 2304 = 64 rows x 36 chunks
    int row = idx / 36, ch = idx - row * 36;
    *(v8s*)&D[(size_t)(mt * 64 + row) * 288 + ch * 8] = *(const v8s*)&smem[row * 296 + ch * 8];
  }
}

// ----------------------- G3: MLP layer 1 deviations ------------------------
__global__ __launch_bounds__(256, 2) void gemm3_kernel(const short* __restrict__ A, const short* __restrict__ B,
                                                       const float* __restrict__ zc,
                                                       const float* __restrict__ hc,
                                                       short* __restrict__ E) {
  __shared__ __align__(16) short smem[18432];
  int t = threadIdx.x, bx = blockIdx.x;           // grid 512, nt-major
  int nt = bx >> 8, mt = bx & 255;
  v4f acc[4][4];
  gemm_core2<288, 288, 288>(A, B, mt, nt, t, acc, smem);
  int l = t & 63, w = t >> 6, wm = w >> 1, wn = w & 1, lane16 = l & 15, q4 = l >> 4;
  int rowbase = mt * 128, colbase = nt * 128;
#pragma unroll
  for (int i = 0; i < 4; ++i)
#pragma unroll
    for (int r = 0; r < 4; ++r) {
      int lr = wm * 64 + i * 16 + q4 * 4 + r;
#pragma unroll
      for (int j = 0; j < 4; ++j) {
        int col_l = wn * 64 + j * 16 + lane16;
        int col_g = colbase + col_l;
        float z = zc[col_g] + acc[i][j][r];
        smem[lr * CP + col_l] = (short)f2b(gelu_fast(z) - hc[col_g]);
      }
    }
  __syncthreads();
#pragma unroll
  for (int k2 = 0; k2 < 8; ++k2) {
    int idx = k2 * 256 + t;
    int row = idx >> 4, c8 = (idx & 15) * 8;
    *(v8s*)&E[(size_t)(rowbase + row) * 256 + colbase + c8] =
        *(const v8s*)&smem[row * CP + c8];
  }
}

// ------- G4: MLP layer 2 deviations, fused transpose-to-output -------------
__global__ __launch_bounds__(256, 2) void gemm4_kernel(const short* __restrict__ A, const short* __restrict__ B,
                                                       const float* __restrict__ oc,
                                                       float* __restrict__ out) {
  __shared__ __align__(16) short smem[18432];
  float* F = (float*)smem;
  int t = threadIdx.x, bx = blockIdx.x;           // grid 512, nt-major
  int nt = bx >> 8, mt = bx & 255;
  v4f acc[4][4];
  gemm_core2<256, 256, 256>(A, B, mt, nt, t, acc, smem);
  int l = t & 63, w = t >> 6, wm = w >> 1, wn = w & 1, lane16 = l & 15, q4 = l >> 4;
  int b_ = mt >> 5;
  int sbase = (mt & 31) * 128;
  for (int q = 0; q < 4; ++q) {
    __syncthreads();
    if (wn == (q >> 1)) {
#pragma unroll
      for (int i = 0; i < 4; ++i)
#pragma unroll
        for (int r = 0; r < 4; ++r) {
          int srow = wm * 64 + i * 16 + q4 * 4 + r;
#pragma unroll
          for (int jj = 0; jj < 2; ++jj) {
            int j = (q & 1) * 2 + jj;
            int c_in = jj * 16 + lane16;
            int col_g = nt * 128 + q * 32 + c_in;
            F[c_in * 132 + srow] = oc[col_g] + acc[i][j][r];
          }
        }
    }
    __syncthreads();
#pragma unroll
    for (int k2 = 0; k2 < 4; ++k2) {
      int idx = k2 * 256 + t;
      int c_loc = idx >> 5, s4 = (idx & 31) * 4;
      v4f vv = *(const v4f*)&F[c_loc * 132 + s4];
      int cg = nt * 128 + q * 32 + c_loc;
      *(v4f*)&out[(size_t)b_ * 1048576 + (size_t)cg * 4096 + sbase + s4] = vv;
    }
  }
}

// ---------------------------------------------------------------------------
extern "C" void kernel_launch(void* const* d_in, const int* in_sizes, int n_in,
                              void* d_out, int out_size, void* d_ws, size_t ws_size,
                              hipStream_t stream) {
  const float* x  = (const float*)d_in[0];
  const float* y  = (const float*)d_in[1];
  const float* fw = (const float*)d_in[2];
  const float* w1 = (const float*)d_in[3];
  const float* b1 = (const float*)d_in[4];
  const float* w2 = (const float*)d_in[5];
  const float* b2 = (const float*)d_in[6];
  float* out = (float*)d_out;
  char* ws = (char*)d_ws;

  // workspace layout (bytes) -- no qbuf anymore (Q eliminated); ~62 MB total
  short* xn   = (short*)(ws + 0);                           // 16777216
  short* mn   = (short*)(ws + 16777216);                    // 1048576
  unsigned long long* packed_part =
      (unsigned long long*)(ws + 17825792);                 // 4194304 (16x32768)
  int*   ind  = (int*)(ws + 22020096);                      // 131072
  float* cnt  = (float*)(ws + 22151168);                    // 8192
  float* sums = (float*)(ws + 22159360);                    // 2129920
  short* nwt  = (short*)(ws + 24289280);                    // 1572864 (384x2048)
  float* colsum = (float*)(ws + 25862144);                  // 1152
  float* c0   = (float*)(ws + 25863296);                    // 1152
  float* zc   = (float*)(ws + 25864448);                    // 1024
  float* hc   = (float*)(ws + 25865472);                    // 1024
  float* oc   = (float*)(ws + 25866496);                    // 1024
  short* w1t  = (short*)(ws + 25867520);                    // 147456 (256x288)
  short* w2t  = (short*)(ws + 26014976);                    // 131072
  short* dbuf = (short*)(ws + 26148864);                    // 18874368 (32768x288)
  short* ebuf = (short*)(ws + 45023232);                    // 16777216
  float* norms  = (float*)(ws + 61800448);                  // 131072
  int*   offs   = (int*)(ws + 61931520);                    // 8704
  int*   cursor = (int*)(ws + 61940224);                    // 8192
  int*   sorted = (int*)(ws + 61948416);                    // 131072
  if (ws_size < 62079488ull) return;  // diagnostic: absmax would be 2.7084e-4

  hipMemsetAsync(cnt,    0, 8192, stream);
  hipMemsetAsync(nwt,    0, 1572864, stream);
  hipMemsetAsync(colsum, 0, 1152, stream);

  transpose_norm_kernel<<<1024, 256, 0, stream>>>(x, xn, norms);
  cbnorm_kernel<<<512, 256, 0, stream>>>(fw, mn);
  gemm1_kernel<<<4096, 256, 0, stream>>>(xn, mn, packed_part);
  ind_kernel<<<128, 256, 0, stream>>>(packed_part, ind, cnt);
  scan_kernel<<<1, 256, 0, stream>>>(cnt, offs, cursor);
  fill_kernel<<<128, 256, 0, stream>>>(ind, cursor, sorted);
  segsum_kernel<<<2048, 256, 0, stream>>>(xn, norms, y, offs, sorted, sums);
  neww_kernel<<<2048, 64, 0, stream>>>(fw, sums, cnt, nwt, colsum);
  const_kernel<<<1, 256, 0, stream>>>(colsum, w1, b1, w2, b2, c0, zc, hc, oc);
  wtrans_kernel<<<512, 64, 0, stream>>>(w1, w2, w1t, w2t);
  attn_kernel<<<512, 256, 0, stream>>>(xn, mn, nwt, colsum, c0, dbuf);
  gemm3_kernel<<<512, 256, 0, stream>>>(dbuf, w1t, zc, hc, ebuf);
  gemm4_kernel<<<512, 256, 0, stream>>>(ebuf, w2t, oc, out);
}